// Round 6
// baseline (237.774 us; speedup 1.0000x reference)
//
#include <hip/hip_runtime.h>

// snnTorch Leaky recurrence, reset='subtract':
//   mem_t = 0.95*mem_{t-1} + x_t - spk_{t-1};  spk_t = (mem_t > 1)
// N=8192 independent chains, T=4000 sequential.
//
// R13: CONTROL - byte-identical resubmission of the R8 kernel that passed at
// 235.97us (absmax 0.0) in Round 1. R9-R12 (3 asm variants + 1 pure-C++
// algebraic variant with scaffold identical to this file) all failed with
// bit-identical statistics (driver absmax 468.0 / pytest absmax 1.0).
// Driver absmax 468.0 is impossible for any executed version of this code
// (expand writes only 0.0f/1.0f), implicating the environment, not the
// source. This run discriminates: pass => env healthy, R9-R12 were real
// bugs, resume minimal-diff from here; fail => all results since Round 2
// are invalid.
//
// R8: quad-per-row cooperative streaming. R1-R7 post-mortems showed every
// lane-per-row structure pays ~200-330 cyc per 16B quantum because each
// float4 load instruction carries 64 divergent addresses (stride 16000B) =
// 64 cache-line segments the vmem pipe processes serially. Fix: 4 lanes per
// row. Lane 4r+j streams quanta q==j (mod 4) of row r, so one wave load =
// 16 rows x 64 CONTIGUOUS bytes (16 full-line segments, 4x fewer, 0 waste),
// and wave count rises 128->512 (2 blocks/CU). All 4 lanes recompute the
// serial chain redundantly (free: issue cost is per-wave-instruction); x
// values are spread quad-internally with v_mov_b32_dpp quad_perm broadcasts
// (pure VALU, no LDS). Ring of 8 float4/lane = 128-step flight per load.
//
// Numerics: exact reference rounding ((0.95*mem + x) - r) via __f*_rn, no
// fma contraction - verified absmax 0.0 in R1-R7. Spike bits accumulated as
// acc = fma(r, 2^sh, acc): r in {0,1}, shifts are powers of two, partial
// sums < 2^16 -> every fma is exact; cvt_u32 exact. Pack layout identical
// to R4-R7 (word = packgroup>>3, nibble = (packgroup&7)*4), expand kernel
// unchanged.

namespace {

constexpr int T_LEN = 4000;
constexpr int N_NEU = 8192;
constexpr int QROW  = 128;   // packed row stride in u32 (125 used)

__device__ __forceinline__ void stepf(float xv, float& mem, float& r,
                                      float& acc, float bit) {
    float t = __fmul_rn(0.95f, mem);
    t       = __fadd_rn(t, xv);
    mem     = __fsub_rn(t, r);      // r = spike_{t-1} = reset_t
    bool s  = mem > 1.0f;
    r   = s ? 1.0f : 0.0f;          // spike_t == reset_{t+1}
    acc = __fmaf_rn(r, bit, acc);   // exact: r in {0,1}, bit = 2^sh, acc < 2^16
}

// broadcast from lane (quad_base + J) to all 4 lanes of the quad (VALU dpp)
template<int J>
__device__ __forceinline__ float qb(float v) {
    return __int_as_float(
        __builtin_amdgcn_mov_dpp(__float_as_int(v), J * 0x55, 0xF, 0xF, true));
}
template<int J>
__device__ __forceinline__ float4 qb4(const float4 v) {
    float4 o;
    o.x = qb<J>(v.x); o.y = qb<J>(v.y); o.z = qb<J>(v.z); o.w = qb<J>(v.w);
    return o;
}

// One 16-step big-group from ring slot SLOT (quanta 4g+0..4g+3 held by quad
// lanes 0..3). Optionally refill SLOT with group g+8 (p points at group g&~7
// base for this lane). Returns the 16 spike bits.
template<int SLOT, bool REFILL>
__device__ __forceinline__ unsigned group16(const float* __restrict__ p,
                                            float4* __restrict__ ring,
                                            float& mem, float& r) {
    float4 a0 = qb4<0>(ring[SLOT]);   // steps 16g+0 .. +3
    float4 a1 = qb4<1>(ring[SLOT]);   // steps 16g+4 .. +7
    float4 a2 = qb4<2>(ring[SLOT]);   // steps 16g+8 .. +11
    float4 a3 = qb4<3>(ring[SLOT]);   // steps 16g+12.. +15
    if (REFILL)   // slot value already captured by the broadcasts above
        ring[SLOT] = *reinterpret_cast<const float4*>(p + 128 + 16 * SLOT);
    float acc = 0.0f;
    stepf(a0.x, mem, r, acc, 1.f);      stepf(a0.y, mem, r, acc, 2.f);
    stepf(a0.z, mem, r, acc, 4.f);      stepf(a0.w, mem, r, acc, 8.f);
    stepf(a1.x, mem, r, acc, 16.f);     stepf(a1.y, mem, r, acc, 32.f);
    stepf(a1.z, mem, r, acc, 64.f);     stepf(a1.w, mem, r, acc, 128.f);
    stepf(a2.x, mem, r, acc, 256.f);    stepf(a2.y, mem, r, acc, 512.f);
    stepf(a2.z, mem, r, acc, 1024.f);   stepf(a2.w, mem, r, acc, 2048.f);
    stepf(a3.x, mem, r, acc, 4096.f);   stepf(a3.y, mem, r, acc, 8192.f);
    stepf(a3.z, mem, r, acc, 16384.f);  stepf(a3.w, mem, r, acc, 32768.f);
    __builtin_amdgcn_sched_barrier(0);  // keep refills inside their group
    return (unsigned)acc;               // exact integer < 2^16
}

__global__ __launch_bounds__(64, 1)
void snn_scan(const float* __restrict__ x, unsigned* __restrict__ q) {
    const int l    = threadIdx.x;
    const int j    = l & 3;                       // quad phase (quantum mod 4)
    const int n    = blockIdx.x * 16 + (l >> 2);  // this quad's neuron row
    const bool lead = (j == 0);

    // lane streams quanta 4g+j: float offset 16g + 4j  (64 B/row contiguous
    // per wave-instruction across the quad)
    const float* p = x + (size_t)n * T_LEN + 4 * j;
    unsigned* qn   = q + (size_t)n * QROW;

    float mem = 0.0f;   // mem_0 = 0
    float r   = 0.0f;   // reset_1 = H(0-1) = 0

    float4 ring[8];     // 32 VGPRs, all indices static
#pragma unroll
    for (int i = 0; i < 8; ++i)
        ring[i] = *reinterpret_cast<const float4*>(p + 16 * i);

    // Main: 30 iters x 8 groups = groups 0..239 (words 0..119), full refill.
#pragma unroll 1
    for (int k = 0; k < 30; ++k) {
        unsigned u0 = group16<0, true>(p, ring, mem, r);
        unsigned u1 = group16<1, true>(p, ring, mem, r);
        unsigned u2 = group16<2, true>(p, ring, mem, r);
        unsigned u3 = group16<3, true>(p, ring, mem, r);
        unsigned u4 = group16<4, true>(p, ring, mem, r);
        unsigned u5 = group16<5, true>(p, ring, mem, r);
        unsigned u6 = group16<6, true>(p, ring, mem, r);
        unsigned u7 = group16<7, true>(p, ring, mem, r);
        if (lead)
            *reinterpret_cast<uint4*>(qn) =
                make_uint4(u0 | (u1 << 16), u2 | (u3 << 16),
                           u4 | (u5 << 16), u6 | (u7 << 16));
        qn += 4;
        p  += 128;
    }
    // Iter 30: groups 240..247 (words 120..123); refill only groups 248,249.
    {
        unsigned u0 = group16<0, true >(p, ring, mem, r);
        unsigned u1 = group16<1, true >(p, ring, mem, r);
        unsigned u2 = group16<2, false>(p, ring, mem, r);
        unsigned u3 = group16<3, false>(p, ring, mem, r);
        unsigned u4 = group16<4, false>(p, ring, mem, r);
        unsigned u5 = group16<5, false>(p, ring, mem, r);
        unsigned u6 = group16<6, false>(p, ring, mem, r);
        unsigned u7 = group16<7, false>(p, ring, mem, r);
        if (lead)
            *reinterpret_cast<uint4*>(qn) =
                make_uint4(u0 | (u1 << 16), u2 | (u3 << 16),
                           u4 | (u5 << 16), u6 | (u7 << 16));
        qn += 4;
        p  += 128;
    }
    // Epilogue: groups 248,249 from slots 0,1 -> word 124.
    unsigned e0 = group16<0, false>(p, ring, mem, r);
    unsigned e1 = group16<1, false>(p, ring, mem, r);
    if (lead)
        qn[0] = e0 | (e1 << 16);
}

// Expand packed nibbles -> float spikes, fully coalesced float4 writes.
// 8192*1000 float4s = 32000 blocks x 256 threads exactly. (unchanged)
__global__ __launch_bounds__(256)
void snn_expand(const unsigned* __restrict__ q, float* __restrict__ out) {
    const unsigned i = blockIdx.x * 256 + threadIdx.x;  // float4 index
    const unsigned n = i / 1000u;                       // neuron row
    const unsigned c = i - n * 1000u;                   // float4 col
    const unsigned w = q[n * QROW + (c >> 3)];
    const unsigned nib = w >> ((c & 7u) * 4u);
    float4 f;
    f.x = (nib & 1u) ? 1.0f : 0.0f;
    f.y = (nib & 2u) ? 1.0f : 0.0f;
    f.z = (nib & 4u) ? 1.0f : 0.0f;
    f.w = (nib & 8u) ? 1.0f : 0.0f;
    reinterpret_cast<float4*>(out)[i] = f;
}

} // namespace

extern "C" void kernel_launch(void* const* d_in, const int* in_sizes, int n_in,
                              void* d_out, int out_size, void* d_ws, size_t ws_size,
                              hipStream_t stream) {
    const float* x = (const float*)d_in[0];
    float* out     = (float*)d_out;
    unsigned* q    = (unsigned*)d_ws;   // >= 4 MiB (verified R4-R6)
    snn_scan<<<dim3(N_NEU / 16), dim3(64), 0, stream>>>(x, q);
    snn_expand<<<dim3(32000), dim3(256), 0, stream>>>(q, out);
}

// Round 8
// 235.639 us; speedup vs baseline: 1.0091x; 1.0091x over previous
//
#include <hip/hip_runtime.h>

// snnTorch Leaky recurrence, reset='subtract':
//   mem_t = 0.95*mem_{t-1} + x_t - spk_{t-1};  spk_t = (mem_t > 1)
// N=8192 independent chains, T=4000 sequential.
//
// R15: cluster-pinned loop rotation. Value-level lanes are closed: asm
// rewrites (R9-R11) and the algebraic 2-op-cycle reformulation (R12/R14)
// all fail correctness (R13 pass / R14 fail with step-math as the only diff
// is conclusive). This round changes INSTRUCTION ORDER ONLY: each step is
// written in rotated form  [sub_t, mul_t, cmp_t, add_t, cndmask_t, fmac_t]
// and pinned as a cluster with __builtin_amdgcn_sched_barrier(0) (a
// compile-time scheduling fence emitting zero instructions). Every computed
// value and every rounding is IDENTICAL to the verified R13 kernel -- the
// statements are the same, merely reassigned across loop iterations
// (rotation) and fenced. Why it should help: R13's 58us scan = ~35 cyc/step
// = the 6-op step emitted serially, but the DAG's carried cycles are two
// PARALLEL 3-op chains (mem: mul->add->sub; r: cmp->cndmask->sub). Pinned
// rotated clusters let in-order issue overlap them:
//   sub@0 -> {mul,cmp}@~5 -> {add,cndmask}@~10 -> next sub@~15-20
// -> ~18-23 cyc/step -> scan ~30-38us. Worst case the hint is ignored ->
// neutral, values still exact.
//
// Memory structure identical to verified R8/R13 (absmax 0.0): 4 lanes/row,
// 16 rows/wave, 64B-contiguous wave loads, 8-deep float4 ring (128-step
// flight), dpp quad broadcasts, nibble-packed spikes (R4 layout), separate
// coalesced expand kernel.

namespace {

constexpr int T_LEN = 4000;
constexpr int N_NEU = 8192;
constexpr int QROW  = 128;   // packed row stride in u32 (125 used)

// broadcast from lane (quad_base + J) to all 4 lanes of the quad (VALU dpp)
template<int J>
__device__ __forceinline__ float qb(float v) {
    return __int_as_float(
        __builtin_amdgcn_mov_dpp(__float_as_int(v), J * 0x55, 0xF, 0xF, true));
}
template<int J>
__device__ __forceinline__ float4 qb4(const float4 v) {
    float4 o;
    o.x = qb<J>(v.x); o.y = qb<J>(v.y); o.z = qb<J>(v.z); o.w = qb<J>(v.w);
    return o;
}

// Rotated step t (t = 0..14 of a 16-step group). Entering: h = head value
// RN(RN(0.95*mem_{t-1}) + x_t), r = spike_{t-1}. Computes step t fully and
// the HEAD of step t+1 (mul+add do not depend on r_t -> overlaps the
// cmp/cndmask chain). All ops identical to R13's stepf, just rotated.
__device__ __forceinline__ void step_rot(float xnext, float bit, float& h,
                                         float& mem, float& r, float& acc) {
    mem      = __fsub_rn(h, r);        // mem_t      (R13: sub of step t)
    float tm = __fmul_rn(0.95f, mem);  // head mul   (R13: mul of step t+1)
    bool s   = mem > 1.0f;             // spk_t
    h        = __fadd_rn(tm, xnext);   // head add   (R13: add of step t+1)
    r        = s ? 1.0f : 0.0f;        // reset_{t+1}
    acc      = __fmaf_rn(r, bit, acc); // record spk_t (exact: bit = 2^t)
    __builtin_amdgcn_sched_barrier(0); // pin this step's cluster
}

// One 16-step group from ring slot SLOT (quanta held by quad lanes 0..3).
// Optionally refill SLOT with the group 8 ahead (128-step flight).
// Returns the 16 spike bits (bit t = spike of step t; R4 layout).
template<int SLOT, bool REFILL>
__device__ __forceinline__ unsigned group16(const float* __restrict__ p,
                                            float4* __restrict__ ring,
                                            float& mem, float& r) {
    float4 a0 = qb4<0>(ring[SLOT]);   // x for steps 0..3
    float4 a1 = qb4<1>(ring[SLOT]);   // x for steps 4..7
    float4 a2 = qb4<2>(ring[SLOT]);   // x for steps 8..11
    float4 a3 = qb4<3>(ring[SLOT]);   // x for steps 12..15
    if (REFILL)   // slot value already captured by the broadcasts above
        ring[SLOT] = *reinterpret_cast<const float4*>(p + 128 + 16 * SLOT);
    float acc = 0.0f;
    // group prologue: head of step 0 (R13's mul+add of step 0)
    float h = __fadd_rn(__fmul_rn(0.95f, mem), a0.x);
    __builtin_amdgcn_sched_barrier(0);
    step_rot(a0.y, 1.f,     h, mem, r, acc);   // t=0
    step_rot(a0.z, 2.f,     h, mem, r, acc);   // t=1
    step_rot(a0.w, 4.f,     h, mem, r, acc);   // t=2
    step_rot(a1.x, 8.f,     h, mem, r, acc);   // t=3
    step_rot(a1.y, 16.f,    h, mem, r, acc);   // t=4
    step_rot(a1.z, 32.f,    h, mem, r, acc);   // t=5
    step_rot(a1.w, 64.f,    h, mem, r, acc);   // t=6
    step_rot(a2.x, 128.f,   h, mem, r, acc);   // t=7
    step_rot(a2.y, 256.f,   h, mem, r, acc);   // t=8
    step_rot(a2.z, 512.f,   h, mem, r, acc);   // t=9
    step_rot(a2.w, 1024.f,  h, mem, r, acc);   // t=10
    step_rot(a3.x, 2048.f,  h, mem, r, acc);   // t=11
    step_rot(a3.y, 4096.f,  h, mem, r, acc);   // t=12
    step_rot(a3.z, 8192.f,  h, mem, r, acc);   // t=13
    step_rot(a3.w, 16384.f, h, mem, r, acc);   // t=14
    // final step t=15 (no next head; identical ops to R13's last step)
    mem    = __fsub_rn(h, r);
    bool s = mem > 1.0f;
    r      = s ? 1.0f : 0.0f;
    acc    = __fmaf_rn(r, 32768.f, acc);
    __builtin_amdgcn_sched_barrier(0);  // keep refills inside their group
    return (unsigned)acc;               // exact integer < 2^16
}

__global__ __launch_bounds__(64, 1)
void snn_scan(const float* __restrict__ x, unsigned* __restrict__ q) {
    const int l    = threadIdx.x;
    const int j    = l & 3;                       // quad phase (quantum mod 4)
    const int n    = blockIdx.x * 16 + (l >> 2);  // this quad's neuron row
    const bool lead = (j == 0);

    // lane streams quanta 4g+j: float offset 16g + 4j  (64 B/row contiguous
    // per wave-instruction across the quad)
    const float* p = x + (size_t)n * T_LEN + 4 * j;
    unsigned* qn   = q + (size_t)n * QROW;

    float mem = 0.0f;   // mem_0 = 0
    float r   = 0.0f;   // reset_1 = H(0-1) = 0

    float4 ring[8];     // 32 VGPRs, all indices static
#pragma unroll
    for (int i = 0; i < 8; ++i)
        ring[i] = *reinterpret_cast<const float4*>(p + 16 * i);

    // Main: 30 iters x 8 groups = groups 0..239 (words 0..119), full refill.
#pragma unroll 1
    for (int k = 0; k < 30; ++k) {
        unsigned u0 = group16<0, true>(p, ring, mem, r);
        unsigned u1 = group16<1, true>(p, ring, mem, r);
        unsigned u2 = group16<2, true>(p, ring, mem, r);
        unsigned u3 = group16<3, true>(p, ring, mem, r);
        unsigned u4 = group16<4, true>(p, ring, mem, r);
        unsigned u5 = group16<5, true>(p, ring, mem, r);
        unsigned u6 = group16<6, true>(p, ring, mem, r);
        unsigned u7 = group16<7, true>(p, ring, mem, r);
        if (lead)
            *reinterpret_cast<uint4*>(qn) =
                make_uint4(u0 | (u1 << 16), u2 | (u3 << 16),
                           u4 | (u5 << 16), u6 | (u7 << 16));
        qn += 4;
        p  += 128;
    }
    // Iter 30: groups 240..247 (words 120..123); refill only groups 248,249.
    {
        unsigned u0 = group16<0, true >(p, ring, mem, r);
        unsigned u1 = group16<1, true >(p, ring, mem, r);
        unsigned u2 = group16<2, false>(p, ring, mem, r);
        unsigned u3 = group16<3, false>(p, ring, mem, r);
        unsigned u4 = group16<4, false>(p, ring, mem, r);
        unsigned u5 = group16<5, false>(p, ring, mem, r);
        unsigned u6 = group16<6, false>(p, ring, mem, r);
        unsigned u7 = group16<7, false>(p, ring, mem, r);
        if (lead)
            *reinterpret_cast<uint4*>(qn) =
                make_uint4(u0 | (u1 << 16), u2 | (u3 << 16),
                           u4 | (u5 << 16), u6 | (u7 << 16));
        qn += 4;
        p  += 128;
    }
    // Epilogue: groups 248,249 from slots 0,1 -> word 124.
    unsigned e0 = group16<0, false>(p, ring, mem, r);
    unsigned e1 = group16<1, false>(p, ring, mem, r);
    if (lead)
        qn[0] = e0 | (e1 << 16);
}

// Expand packed nibbles -> float spikes, fully coalesced float4 writes.
// 8192*1000 float4s = 32000 blocks x 256 threads exactly. (unchanged)
__global__ __launch_bounds__(256)
void snn_expand(const unsigned* __restrict__ q, float* __restrict__ out) {
    const unsigned i = blockIdx.x * 256 + threadIdx.x;  // float4 index
    const unsigned n = i / 1000u;                       // neuron row
    const unsigned c = i - n * 1000u;                   // float4 col
    const unsigned w = q[n * QROW + (c >> 3)];
    const unsigned nib = w >> ((c & 7u) * 4u);
    float4 f;
    f.x = (nib & 1u) ? 1.0f : 0.0f;
    f.y = (nib & 2u) ? 1.0f : 0.0f;
    f.z = (nib & 4u) ? 1.0f : 0.0f;
    f.w = (nib & 8u) ? 1.0f : 0.0f;
    reinterpret_cast<float4*>(out)[i] = f;
}

} // namespace

extern "C" void kernel_launch(void* const* d_in, const int* in_sizes, int n_in,
                              void* d_out, int out_size, void* d_ws, size_t ws_size,
                              hipStream_t stream) {
    const float* x = (const float*)d_in[0];
    float* out     = (float*)d_out;
    unsigned* q    = (unsigned*)d_ws;   // >= 4 MiB (verified R4-R8, R13)
    snn_scan<<<dim3(N_NEU / 16), dim3(64), 0, stream>>>(x, q);
    snn_expand<<<dim3(32000), dim3(256), 0, stream>>>(q, out);
}